// Round 4
// baseline (995.069 us; speedup 1.0000x reference)
//
#include <hip/hip_runtime.h>
#include <hip/hip_bf16.h>
#include <math.h>

// Problem dims (fixed by the reference)
#define PB 8
#define PS 4096
#define PD 1024

typedef __attribute__((ext_vector_type(8))) short bf16x8;
typedef __attribute__((ext_vector_type(4))) float f32x4;

__device__ __forceinline__ ushort f2b(float f) {
    // round-to-nearest-even f32 -> bf16
    unsigned u = __float_as_uint(f);
    unsigned r = (u + 0x7FFFu + ((u >> 16) & 1u)) >> 16;
    return (ushort)r;
}
__device__ __forceinline__ float b2f(ushort h) {
    return __uint_as_float(((unsigned)h) << 16);
}

__device__ __forceinline__ void gl2lds16(const void* g, void* l) {
    // async global->LDS, 16B/lane; LDS dest is wave-uniform base + lane*16
    __builtin_amdgcn_global_load_lds(
        (const __attribute__((address_space(1))) void*)g,
        (__attribute__((address_space(3))) void*)l, 16, 0, 0);
}

__global__ __launch_bounds__(256) void cvt_f32_bf16(const float* __restrict__ in,
                                                    ushort* __restrict__ out, int n) {
    int i = (blockIdx.x * 256 + threadIdx.x) * 4;
    if (i + 3 < n) {
        float4 v = *(const float4*)(in + i);
        ushort4 o;
        o.x = f2b(v.x); o.y = f2b(v.y); o.z = f2b(v.z); o.w = f2b(v.w);
        *(ushort4*)(out + i) = o;
    }
}

// both weight matrices in one dispatch
__global__ __launch_bounds__(256) void cvt_w2(const float* __restrict__ Wu,
                                              const float* __restrict__ Wf,
                                              ushort* __restrict__ Wub,
                                              ushort* __restrict__ Wfb, int n) {
    int i = (blockIdx.x * 256 + threadIdx.x) * 4;
    const float* in = (i < n) ? Wu : Wf;
    ushort* out = (i < n) ? Wub : Wfb;
    int j = (i < n) ? i : i - n;
    float4 v = *(const float4*)(in + j);
    ushort4 o;
    o.x = f2b(v.x); o.y = f2b(v.y); o.z = f2b(v.z); o.w = f2b(v.w);
    *(ushort4*)(out + j) = o;
}

// C = A (MxK, row-major bf16) * Bm^T (Bm is NxK row-major bf16) + bias
//
// 256x256 tile, BK=64, 512 threads = 8 waves (2M x 4N), per-wave 128x64 out.
// 4 phases per K-tile, fragments read ONE PHASE AHEAD of their MFMA so the
// per-phase lgkmcnt(0) drain overlaps the previous MFMA cluster (LDS pipe and
// matrix pipe busy simultaneously).  Per phase (tile u, slot s = u&1):
//   P1: stage A-h0(u+2)      ; read bf1 (slot s, B h1, 4)  ; MFMA(0,0) af0 x bf0
//   P2: stage B-n0(u+2)      ; read af1 (slot s, A h1, 8)  ; MFMA(0,1) af0 x bf1
//       vmcnt(4)  <- tile u+1 fully landed; tile u+2's h0/n0 stay in flight
//   P3: stage B-n1(u+2)      ; read af0' (slot s^1, A h0, 8); MFMA(1,0) af1 x bf0
//   P4: stage A-h1(u+2)      ; read bf0' (slot s^1, B h0, 4); MFMA(1,1) af1 x bf1
// Each phase ends with lgkmcnt(0) (drains this phase's reads, issued before the
// MFMA -> drained during it) + one barrier (protects the death-ordered staging
// overwrites). Cross-tile fragments (af0/bf0) are double-buffered via named
// register sets with a x2-unrolled tile loop (static indexing only).
//
// LDS regions (per slot, 16 KB each):
//   A-h: block rows {h*64..+63} u {128+h*64..+63}   (dead after its af reads)
//   B-h: Bm rows {wn*64+h*32..+31} for all wn       (dead after its bf reads)
// K-granule XOR swizzle (slot granule g of LDS row r holds logical granule
// g^(r&7)), applied on the GLOBAL address side of the DMA; verified
// conflict-free (SQ_LDS_BANK_CONFLICT = 0) and numerically correct in r2.
//
// Deadlock audit (r3->r4): all s_barriers execute under block-uniform
// conditions; vmcnt counts close (8 lines/tile/wave, checkpoint leaves 4 in
// flight, tail drains with vmcnt(0)); every staged LDS region has
// lgkmcnt(0)+barrier between its last ds_read and the overwriting DMA issue.
template <bool OUT_BF16>
__global__ __launch_bounds__(512, 2) void gemm_bt(const ushort* __restrict__ A,
                                                  const ushort* __restrict__ Bm,
                                                  const float* __restrict__ bias,
                                                  void* __restrict__ C,
                                                  int M, int N, int K) {
    __shared__ ushort As[2 * 16384];   // 64 KB: slot*16384 + h*8192 + line*4096 + row*64
    __shared__ ushort Bs[2 * 16384];   // 64 KB

    const int tid = threadIdx.x;
    const int lane = tid & 63;
    const int wave = tid >> 6;                 // 0..7
    const int nbn = N >> 8;                    // 4
    // XCD-aware mapping: XCD = blockIdx % 8; bn fastest within an XCD.
    const int xcd = blockIdx.x & 7;
    const int g = blockIdx.x >> 3;
    const int bpx = (gridDim.x >> 3) / nbn;
    const int bm = xcd * bpx + g / nbn;
    const int bn = g % nbn;
    const int wm = wave >> 2, wn = wave & 3;   // 2 x 4 wave grid
    const int l15 = lane & 15, quad = lane >> 4;

    // ---- staging addresses (per-lane global, wave-uniform LDS) ----
    const int qa = wave * 8 + (lane >> 3);            // row within a 64-row line
    const int sg = ((lane & 7) ^ (qa & 7)) * 8;       // swizzled k-granule (elems)
    const ushort* Ag = A + (size_t)(bm * 256 + qa) * K + sg;
    const int brow0 = bn * 256 + ((qa >> 5) << 6) + (qa & 31);
    const ushort* Bg = Bm + (size_t)brow0 * K + sg;
    const int ldst = wave * 512;                       // wave-uniform elems

#define SA(v, h, c)                                                             \
    gl2lds16(Ag + (size_t)((c) * 128 + (h) * 64) * K + (size_t)(v) * 64,        \
             As + (((v) & 1) * 16384 + (h) * 8192 + (c) * 4096 + ldst))
#define SB(v, h, d)                                                             \
    gl2lds16(Bg + (size_t)((d) * 128 + (h) * 32) * K + (size_t)(v) * 64,        \
             Bs + (((v) & 1) * 16384 + (h) * 8192 + (d) * 4096 + ldst))

    // ---- compute-side per-thread constants ----
    const int aro = (wm * 64 + l15) * 64;   // + h*8192 + i*1024 (+slot)
    const int bro = (wn * 32 + l15) * 64;   // + h*8192 + j*1024 (+slot)
    const int sw = l15 & 7;
    const int k0off = (quad ^ sw) * 8;
    const int k1off = ((4 + quad) ^ sw) * 8;

    f32x4 acc[8][4];
#pragma unroll
    for (int i = 0; i < 8; ++i)
#pragma unroll
        for (int j = 0; j < 4; ++j) acc[i][j] = (f32x4){0.f, 0.f, 0.f, 0.f};

    // cross-tile (h0) fragment sets: even/odd tiles ping-pong; within-tile
    // (h1) fragments are single-buffered (read and consumed inside one tile).
    bf16x8 afE[4][2], bfE[2][2], afO[4][2], bfO[2][2];
    bf16x8 af1[4][2], bf1[2][2];

#define MFMA_Q(mq, nq, AF, BF)                                                  \
    do {                                                                        \
        __builtin_amdgcn_s_setprio(1);                                          \
        _Pragma("unroll") for (int kk = 0; kk < 2; ++kk)                        \
        _Pragma("unroll") for (int i = 0; i < 4; ++i)                           \
        _Pragma("unroll") for (int j = 0; j < 2; ++j)                           \
            acc[(mq) * 4 + i][(nq) * 2 + j] = __builtin_amdgcn_mfma_f32_16x16x32_bf16( \
                AF[i][kk], BF[j][kk], acc[(mq) * 4 + i][(nq) * 2 + j], 0, 0, 0); \
        __builtin_amdgcn_s_setprio(0);                                          \
    } while (0)

#define TILE(u, SL, AF0C, BF0C, AF0N, BF0N)                                     \
    do {                                                                        \
        const ushort* Asl = As + (SL) * 16384;                                  \
        const ushort* Bsl = Bs + (SL) * 16384;                                  \
        const ushort* Asn = As + ((SL) ^ 1) * 16384;                            \
        const ushort* Bsn = Bs + ((SL) ^ 1) * 16384;                            \
        const bool st = (u) + 2 < nt;                                           \
        const bool rd = (u) + 1 < nt;                                           \
        /* P1: quadrant (0,0) */                                                \
        if (st) { SA((u) + 2, 0, 0); SA((u) + 2, 0, 1); }                       \
        _Pragma("unroll") for (int j = 0; j < 2; ++j) {                         \
            bf1[j][0] = *(const bf16x8*)(Bsl + 8192 + j * 1024 + bro + k0off);  \
            bf1[j][1] = *(const bf16x8*)(Bsl + 8192 + j * 1024 + bro + k1off);  \
        }                                                                       \
        MFMA_Q(0, 0, AF0C, BF0C);                                               \
        asm volatile("s_waitcnt lgkmcnt(0)" ::: "memory");                      \
        __builtin_amdgcn_s_barrier();                                           \
        /* P2: quadrant (0,1) */                                                \
        if (st) { SB((u) + 2, 0, 0); SB((u) + 2, 0, 1); }                       \
        _Pragma("unroll") for (int i = 0; i < 4; ++i) {                         \
            af1[i][0] = *(const bf16x8*)(Asl + 8192 + i * 1024 + aro + k0off);  \
            af1[i][1] = *(const bf16x8*)(Asl + 8192 + i * 1024 + aro + k1off);  \
        }                                                                       \
        MFMA_Q(0, 1, AF0C, bf1);                                                \
        if (st) asm volatile("s_waitcnt vmcnt(4)" ::: "memory");                \
        else    asm volatile("s_waitcnt vmcnt(0)" ::: "memory");                \
        asm volatile("s_waitcnt lgkmcnt(0)" ::: "memory");                      \
        __builtin_amdgcn_s_barrier();                                           \
        /* P3: quadrant (1,0); prefetch next tile's A-h0 frags from slot^1 */   \
        if (st) { SB((u) + 2, 1, 0); SB((u) + 2, 1, 1); }                       \
        if (rd) {                                                               \
            _Pragma("unroll") for (int i = 0; i < 4; ++i) {                     \
                AF0N[i][0] = *(const bf16x8*)(Asn + i * 1024 + aro + k0off);    \
                AF0N[i][1] = *(const bf16x8*)(Asn + i * 1024 + aro + k1off);    \
            }                                                                   \
        }                                                                       \
        MFMA_Q(1, 0, af1, BF0C);                                                \
        asm volatile("s_waitcnt lgkmcnt(0)" ::: "memory");                      \
        __builtin_amdgcn_s_barrier();                                           \
        /* P4: quadrant (1,1); prefetch next tile's B-h0 frags from slot^1 */   \
        if (st) { SA((u) + 2, 1, 0); SA((u) + 2, 1, 1); }                       \
        if (rd) {                                                               \
            _Pragma("unroll") for (int j = 0; j < 2; ++j) {                     \
                BF0N[j][0] = *(const bf16x8*)(Bsn + j * 1024 + bro + k0off);    \
                BF0N[j][1] = *(const bf16x8*)(Bsn + j * 1024 + bro + k1off);    \
            }                                                                   \
        }                                                                       \
        MFMA_Q(1, 1, af1, bf1);                                                 \
        asm volatile("s_waitcnt lgkmcnt(0)" ::: "memory");                      \
        __builtin_amdgcn_s_barrier();                                           \
    } while (0)

    const int nt = K >> 6;   // 16 (even)

    // ---- prologue: tiles 0 and 1 fully issued; wait tile 0; read its P1 frags
    SA(0, 0, 0); SA(0, 0, 1); SB(0, 0, 0); SB(0, 0, 1);
    SB(0, 1, 0); SB(0, 1, 1); SA(0, 1, 0); SA(0, 1, 1);
    SA(1, 0, 0); SA(1, 0, 1); SB(1, 0, 0); SB(1, 0, 1);
    SB(1, 1, 0); SB(1, 1, 1); SA(1, 1, 0); SA(1, 1, 1);
    asm volatile("s_waitcnt vmcnt(8)" ::: "memory");   // tile 0's 8 lines landed
    __builtin_amdgcn_s_barrier();
#pragma unroll
    for (int i = 0; i < 4; ++i) {
        afE[i][0] = *(const bf16x8*)(As + i * 1024 + aro + k0off);
        afE[i][1] = *(const bf16x8*)(As + i * 1024 + aro + k1off);
    }
#pragma unroll
    for (int j = 0; j < 2; ++j) {
        bfE[j][0] = *(const bf16x8*)(Bs + j * 1024 + bro + k0off);
        bfE[j][1] = *(const bf16x8*)(Bs + j * 1024 + bro + k1off);
    }

    for (int tau = 0; tau < (nt >> 1); ++tau) {
        const int u0 = tau * 2;
        TILE(u0,     0, afE, bfE, afO, bfO);
        TILE(u0 + 1, 1, afO, bfO, afE, bfE);
    }
#undef SA
#undef SB
#undef MFMA_Q
#undef TILE

    // epilogue: C/D layout col=lane&15, row=quad*4+reg  [verified m89/m91]
    const int gm0 = bm * 256 + wm * 128;
    const int gn0 = bn * 256 + wn * 64;
    float bv[4];
#pragma unroll
    for (int j = 0; j < 4; ++j) bv[j] = bias[gn0 + j * 16 + l15];
#pragma unroll
    for (int i = 0; i < 8; ++i) {
#pragma unroll
        for (int j = 0; j < 4; ++j) {
            const int col = gn0 + j * 16 + l15;
#pragma unroll
            for (int r = 0; r < 4; ++r) {
                const int row = gm0 + i * 16 + quad * 4 + r;
                float v = acc[i][j][r] + bv[j];
                if (OUT_BF16)
                    ((ushort*)C)[(size_t)row * N + col] = f2b(v);
                else
                    ((float*)C)[(size_t)row * N + col] = v;
            }
        }
    }
}

// Pass A: per (b, chunk) compute affine (A_c scalar, B_c vector of D)
// 4-step batched loads so 4+ ushort4 loads are in flight per wave.
__global__ __launch_bounds__(256) void scan_partial(const ushort* __restrict__ upd,
                                                    const float* __restrict__ mask,
                                                    const float* __restrict__ dp,
                                                    float* __restrict__ Bc,
                                                    float* __restrict__ Ac,
                                                    int S, int D, int C) {
    const int c = blockIdx.x % C;
    const int b = blockIdx.x / C;
    const int L = S / C;
    const int d0 = threadIdx.x * 4;
    const float decay = 1.f / (1.f + expf(-dp[0]));
    const ushort* up = upd + ((size_t)b * S + (size_t)c * L) * D + d0;
    const float* mp = mask + (size_t)b * S + (size_t)c * L;
    float aA = 1.f;
    float b0 = 0.f, b1 = 0.f, b2 = 0.f, b3 = 0.f;
    for (int s0 = 0; s0 < L; s0 += 4) {
        float4 mv = *(const float4*)(mp + s0);
        ushort4 u0 = *(const ushort4*)(up + (size_t)(s0 + 0) * D);
        ushort4 u1 = *(const ushort4*)(up + (size_t)(s0 + 1) * D);
        ushort4 u2 = *(const ushort4*)(up + (size_t)(s0 + 2) * D);
        ushort4 u3 = *(const ushort4*)(up + (size_t)(s0 + 3) * D);
        float m, a;
        m = mv.x; a = m * decay + (1.f - m); aA *= a;
        b0 = a * b0 + m * b2f(u0.x); b1 = a * b1 + m * b2f(u0.y);
        b2 = a * b2 + m * b2f(u0.z); b3 = a * b3 + m * b2f(u0.w);
        m = mv.y; a = m * decay + (1.f - m); aA *= a;
        b0 = a * b0 + m * b2f(u1.x); b1 = a * b1 + m * b2f(u1.y);
        b2 = a * b2 + m * b2f(u1.z); b3 = a * b3 + m * b2f(u1.w);
        m = mv.z; a = m * decay + (1.f - m); aA *= a;
        b0 = a * b0 + m * b2f(u2.x); b1 = a * b1 + m * b2f(u2.y);
        b2 = a * b2 + m * b2f(u2.z); b3 = a * b3 + m * b2f(u2.w);
        m = mv.w; a = m * decay + (1.f - m); aA *= a;
        b0 = a * b0 + m * b2f(u3.x); b1 = a * b1 + m * b2f(u3.y);
        b2 = a * b2 + m * b2f(u3.z); b3 = a * b3 + m * b2f(u3.w);
    }
    *(float4*)(Bc + (size_t)blockIdx.x * D + d0) = make_float4(b0, b1, b2, b3);
    if (threadIdx.x == 0) Ac[blockIdx.x] = aA;
}

// Pass B: serial prefix over C chunks per (b,d) chain; writes incoming state per chunk.
// 128-thread blocks -> 64 blocks: spreads the latency chains over more CUs.
__global__ __launch_bounds__(128) void scan_prefix(const float* __restrict__ Ac,
                                                   const float* __restrict__ Bc,
                                                   float* __restrict__ Mn, int D, int C) {
    int gid = blockIdx.x * 128 + threadIdx.x;  // over B*D
    int b = gid / D;
    int d = gid - b * D;
    float mem = 0.f;
    for (int c = 0; c < C; c += 4) {
        float4 av = *(const float4*)(Ac + b * C + c);
        size_t i0 = ((size_t)(b * C + c)) * D + d;
        float q0 = Bc[i0];
        float q1 = Bc[i0 + D];
        float q2 = Bc[i0 + 2 * (size_t)D];
        float q3 = Bc[i0 + 3 * (size_t)D];
        Mn[i0] = mem;                    mem = av.x * mem + q0;
        Mn[i0 + D] = mem;                mem = av.y * mem + q1;
        Mn[i0 + 2 * (size_t)D] = mem;    mem = av.z * mem + q2;
        Mn[i0 + 3 * (size_t)D] = mem;    mem = av.w * mem + q3;
    }
}

// Pass C: replay each chunk from its incoming state, write mem_seq (bf16)
__global__ __launch_bounds__(256) void scan_final(const ushort* __restrict__ upd,
                                                  const float* __restrict__ mask,
                                                  const float* __restrict__ dp,
                                                  const float* __restrict__ Mn,
                                                  ushort* __restrict__ ms,
                                                  int S, int D, int C) {
    const int c = blockIdx.x % C;
    const int b = blockIdx.x / C;
    const int L = S / C;
    const int d0 = threadIdx.x * 4;
    const float decay = 1.f / (1.f + expf(-dp[0]));
    const ushort* up = upd + ((size_t)b * S + (size_t)c * L) * D + d0;
    ushort* op = ms + ((size_t)b * S + (size_t)c * L) * D + d0;
    const float* mp = mask + (size_t)b * S + (size_t)c * L;
    float4 m0 = *(const float4*)(Mn + (size_t)blockIdx.x * D + d0);
    float v0 = m0.x, v1 = m0.y, v2 = m0.z, v3 = m0.w;
    for (int s0 = 0; s0 < L; s0 += 4) {
        float4 mv = *(const float4*)(mp + s0);
        ushort4 u0 = *(const ushort4*)(up + (size_t)(s0 + 0) * D);
        ushort4 u1 = *(const ushort4*)(up + (size_t)(s0 + 1) * D);
        ushort4 u2 = *(const ushort4*)(up + (size_t)(s0 + 2) * D);
        ushort4 u3 = *(const ushort4*)(up + (size_t)(s0 + 3) * D);
        float m, a;
        ushort4 o;
        m = mv.x; a = m * decay + (1.f - m);
        v0 = a * v0 + m * b2f(u0.x); v1 = a * v1 + m * b2f(u0.y);
        v2 = a * v2 + m * b2f(u0.z); v3 = a * v3 + m * b2f(u0.w);
        o.x = f2b(v0); o.y = f2b(v1); o.z = f2b(v2); o.w = f2b(v3);
        *(ushort4*)(op + (size_t)(s0 + 0) * D) = o;
        m = mv.y; a = m * decay + (1.f - m);
        v0 = a * v0 + m * b2f(u1.x); v1 = a * v1 + m * b2f(u1.y);
        v2 = a * v2 + m * b2f(u1.z); v3 = a * v3 + m * b2f(u1.w);
        o.x = f2b(v0); o.y = f2b(v1); o.z = f2b(v2); o.w = f2b(v3);
        *(ushort4*)(op + (size_t)(s0 + 1) * D) = o;
        m = mv.z; a = m * decay + (1.f - m);
        v0 = a * v0 + m * b2f(u2.x); v1 = a * v1 + m * b2f(u2.y);
        v2 = a * v2 + m * b2f(u2.z); v3 = a * v3 + m * b2f(u2.w);
        o.x = f2b(v0); o.y = f2b(v1); o.z = f2b(v2); o.w = f2b(v3);
        *(ushort4*)(op + (size_t)(s0 + 2) * D) = o;
        m = mv.w; a = m * decay + (1.f - m);
        v0 = a * v0 + m * b2f(u3.x); v1 = a * v1 + m * b2f(u3.y);
        v2 = a * v2 + m * b2f(u3.z); v3 = a * v3 + m * b2f(u3.w);
        o.x = f2b(v0); o.y = f2b(v1); o.z = f2b(v2); o.w = f2b(v3);
        *(ushort4*)(op + (size_t)(s0 + 3) * D) = o;
    }
}

extern "C" void kernel_launch(void* const* d_in, const int* in_sizes, int n_in,
                              void* d_out, int out_size, void* d_ws, size_t ws_size,
                              hipStream_t stream) {
    const float* x    = (const float*)d_in[0];
    const float* mask = (const float*)d_in[1];
    const float* Wu   = (const float*)d_in[2];
    const float* bu   = (const float*)d_in[3];
    const float* Wf   = (const float*)d_in[4];
    const float* bfv  = (const float*)d_in[5];
    const float* dp   = (const float*)d_in[6];

    const int B = PB, S = PS, D = PD;
    const int M = B * S;          // 32768
    const int C = 128;            // scan chunks; L = 32

    // workspace layout (bytes): total ~204 MB
    char* ws = (char*)d_ws;
    ushort* xb   = (ushort*)(ws);                 // 64 MB  bf16 x
    ushort* updb = (ushort*)(ws + 67108864);      // 64 MB  bf16 upd
    ushort* memb = (ushort*)(ws + 134217728);     // 64 MB  bf16 mem_seq
    ushort* Wub  = (ushort*)(ws + 201326592);     // 2 MB
    ushort* Wfb  = (ushort*)(ws + 203423744);     // 2 MB
    float*  Bc   = (float*)(ws + 205520896);      // 4 MB   B*C*D
    float*  Mn   = (float*)(ws + 209715200);      // 4 MB   B*C*D
    float*  Ac   = (float*)(ws + 213909504);      // 4 KB   B*C

    const int nx = B * S * D;
    cvt_f32_bf16<<<nx / 1024, 256, 0, stream>>>(x, xb, nx);
    cvt_w2<<<(2 * D * D) / 1024, 256, 0, stream>>>(Wu, Wf, Wub, Wfb, D * D);

    dim3 g1((M / 256) * (D / 256));  // 512 blocks, %8 == 0 for XCD swizzle
    gemm_bt<true><<<g1, 512, 0, stream>>>(xb, Wub, bu, (void*)updb, M, D, D);

    scan_partial<<<B * C, 256, 0, stream>>>(updb, mask, dp, Bc, Ac, S, D, C);
    scan_prefix<<<(B * D) / 128, 128, 0, stream>>>(Ac, Bc, Mn, D, C);
    scan_final<<<B * C, 256, 0, stream>>>(updb, mask, dp, Mn, memb, S, D, C);

    gemm_bt<false><<<g1, 512, 0, stream>>>(memb, Wfb, bfv, d_out, M, D, D);
}

// Round 5
// 455.546 us; speedup vs baseline: 2.1843x; 2.1843x over previous
//
#include <hip/hip_runtime.h>
#include <hip/hip_bf16.h>
#include <math.h>

// Problem dims (fixed by the reference)
#define PB 8
#define PS 4096
#define PD 1024

typedef __attribute__((ext_vector_type(8))) short bf16x8;
typedef __attribute__((ext_vector_type(4))) float f32x4;

__device__ __forceinline__ ushort f2b(float f) {
    // round-to-nearest-even f32 -> bf16
    unsigned u = __float_as_uint(f);
    unsigned r = (u + 0x7FFFu + ((u >> 16) & 1u)) >> 16;
    return (ushort)r;
}
__device__ __forceinline__ float b2f(ushort h) {
    return __uint_as_float(((unsigned)h) << 16);
}

__device__ __forceinline__ void gl2lds16(const void* g, void* l) {
    // async global->LDS, 16B/lane; LDS dest is wave-uniform base + lane*16
    __builtin_amdgcn_global_load_lds(
        (const __attribute__((address_space(1))) void*)g,
        (__attribute__((address_space(3))) void*)l, 16, 0, 0);
}

__global__ __launch_bounds__(256) void cvt_f32_bf16(const float* __restrict__ in,
                                                    ushort* __restrict__ out, int n) {
    int i = (blockIdx.x * 256 + threadIdx.x) * 4;
    if (i + 3 < n) {
        float4 v = *(const float4*)(in + i);
        ushort4 o;
        o.x = f2b(v.x); o.y = f2b(v.y); o.z = f2b(v.z); o.w = f2b(v.w);
        *(ushort4*)(out + i) = o;
    }
}

// both weight matrices in one dispatch
__global__ __launch_bounds__(256) void cvt_w2(const float* __restrict__ Wu,
                                              const float* __restrict__ Wf,
                                              ushort* __restrict__ Wub,
                                              ushort* __restrict__ Wfb, int n) {
    int i = (blockIdx.x * 256 + threadIdx.x) * 4;
    const float* in = (i < n) ? Wu : Wf;
    ushort* out = (i < n) ? Wub : Wfb;
    int j = (i < n) ? i : i - n;
    float4 v = *(const float4*)(in + j);
    ushort4 o;
    o.x = f2b(v.x); o.y = f2b(v.y); o.z = f2b(v.z); o.w = f2b(v.w);
    *(ushort4*)(out + j) = o;
}

// C = A (MxK, row-major bf16) * Bm^T (Bm is NxK row-major bf16) + bias
//
// 256x256 tile, BK=64, 512 threads = 8 waves (2M x 4N), per-wave 128x64 out.
// 4 phases/K-tile; quadrant order (0,0),(1,0),(0,1),(1,1) chosen so every
// fragment set's registers die exactly one phase before their refill read:
//   P1: stage B-h0(u+2)->s ; read af1(u)  <-s.h1   ; MFMA(0,0) af0*bf0
//   P2: stage A-h0(u+2)->s ; read bf1(u)  <-s.h1   ; MFMA(1,0) af1*bf0
//       vmcnt(8)  [newest8 = h1(u+1)+h0(u+2) -> h0(u+1) landed]  barrier
//   P3: stage A-h1(u+2)->s ; read bf0(u+1)<-s^1.h0 ; MFMA(0,1) af0*bf1 ; barrier
//   P4: stage B-h1(u+2)->s ; read af0(u+1)<-s^1.h0 ; MFMA(1,1) af1*bf1
//       lgkmcnt(0) [staging WAR guard] vmcnt(8) [u+1 fully landed] barrier
// Every read is >=1 phase ahead of its MFMA; the compiler's own counted
// lgkmcnt before each MFMA therefore drains during the PREVIOUS MFMA cluster
// (LDS pipe overlaps matrix pipe). Frag regs af0+af1+bf0+bf1 = 96, acc = 128
// (AGPR, unified file) -> ~249 of the 256/wave budget at 2 waves/SIMD (r4's
// spill lesson: do not exceed this).
// WAR audit: each staged region's last ds_read drains (via the compiler's
// MFMA-gating waitcnt or P4's lgkmcnt(0)) before a barrier that precedes the
// overwriting DMA issue. 3 barriers/tile.
//
// LDS regions (per slot, 16 KB each):
//   A-h: block rows {h*64..+63} u {128+h*64..+63}
//   B-h: Bm rows {wn*64+h*32..+31} for all wn
// K-granule XOR swizzle (slot granule g of LDS row r holds logical granule
// g^(r&7)), applied on the GLOBAL address side of the DMA; verified
// conflict-free (SQ_LDS_BANK_CONFLICT = 0) and numerically correct in r2.
template <bool OUT_BF16>
__global__ __launch_bounds__(512, 2) void gemm_bt(const ushort* __restrict__ A,
                                                  const ushort* __restrict__ Bm,
                                                  const float* __restrict__ bias,
                                                  void* __restrict__ C,
                                                  int M, int N, int K) {
    __shared__ ushort As[2 * 16384];   // 64 KB: slot*16384 + h*8192 + line*4096 + row*64
    __shared__ ushort Bs[2 * 16384];   // 64 KB

    const int tid = threadIdx.x;
    const int lane = tid & 63;
    const int wave = tid >> 6;                 // 0..7
    const int nbn = N >> 8;                    // 4
    // XCD-aware mapping: XCD = blockIdx % 8; bn fastest within an XCD.
    const int xcd = blockIdx.x & 7;
    const int g = blockIdx.x >> 3;
    const int bpx = (gridDim.x >> 3) / nbn;
    const int bm = xcd * bpx + g / nbn;
    const int bn = g % nbn;
    const int wm = wave >> 2, wn = wave & 3;   // 2 x 4 wave grid
    const int l15 = lane & 15, quad = lane >> 4;

    // ---- staging addresses (per-lane global, wave-uniform LDS) ----
    const int qa = wave * 8 + (lane >> 3);            // row within a 64-row line
    const int sg = ((lane & 7) ^ (qa & 7)) * 8;       // swizzled k-granule (elems)
    const ushort* Ag = A + (size_t)(bm * 256 + qa) * K + sg;
    const int brow0 = bn * 256 + ((qa >> 5) << 6) + (qa & 31);
    const ushort* Bg = Bm + (size_t)brow0 * K + sg;
    const int ldst = wave * 512;                       // wave-uniform elems

#define SA(v, h, c)                                                             \
    gl2lds16(Ag + (size_t)((c) * 128 + (h) * 64) * K + (size_t)(v) * 64,        \
             As + (((v) & 1) * 16384 + (h) * 8192 + (c) * 4096 + ldst))
#define SB(v, h, d)                                                             \
    gl2lds16(Bg + (size_t)((d) * 128 + (h) * 32) * K + (size_t)(v) * 64,        \
             Bs + (((v) & 1) * 16384 + (h) * 8192 + (d) * 4096 + ldst))

    // ---- compute-side per-thread constants ----
    const int aro = (wm * 64 + l15) * 64;   // + h*8192 + i*1024 (+slot)
    const int bro = (wn * 32 + l15) * 64;   // + h*8192 + j*1024 (+slot)
    const int sw = l15 & 7;
    const int k0off = (quad ^ sw) * 8;
    const int k1off = ((4 + quad) ^ sw) * 8;

    f32x4 acc[8][4];
#pragma unroll
    for (int i = 0; i < 8; ++i)
#pragma unroll
        for (int j = 0; j < 4; ++j) acc[i][j] = (f32x4){0.f, 0.f, 0.f, 0.f};

    // single-buffered fragment sets; refills target registers that died the
    // previous phase (no ping-pong -> no spill; r4 lesson)
    bf16x8 af0[4][2], af1[4][2], bf0[2][2], bf1[2][2];

#define MFMA_Q(mq, nq, AF, BF)                                                  \
    do {                                                                        \
        __builtin_amdgcn_s_setprio(1);                                          \
        _Pragma("unroll") for (int kk = 0; kk < 2; ++kk)                        \
        _Pragma("unroll") for (int i = 0; i < 4; ++i)                           \
        _Pragma("unroll") for (int j = 0; j < 2; ++j)                           \
            acc[(mq) * 4 + i][(nq) * 2 + j] = __builtin_amdgcn_mfma_f32_16x16x32_bf16( \
                AF[i][kk], BF[j][kk], acc[(mq) * 4 + i][(nq) * 2 + j], 0, 0, 0); \
        __builtin_amdgcn_s_setprio(0);                                          \
    } while (0)

    const int nt = K >> 6;   // 16

    // ---- prologue: issue tiles 0,1 (order B-h0,A-h0,A-h1,B-h1 per tile);
    // vmcnt(8) -> tile 0's 8 lines landed; preload af0/bf0 of tile 0.
    SB(0, 0, 0); SB(0, 0, 1); SA(0, 0, 0); SA(0, 0, 1);
    SA(0, 1, 0); SA(0, 1, 1); SB(0, 1, 0); SB(0, 1, 1);
    SB(1, 0, 0); SB(1, 0, 1); SA(1, 0, 0); SA(1, 0, 1);
    SA(1, 1, 0); SA(1, 1, 1); SB(1, 1, 0); SB(1, 1, 1);
    asm volatile("s_waitcnt vmcnt(8)" ::: "memory");
    __builtin_amdgcn_s_barrier();
#pragma unroll
    for (int i = 0; i < 4; ++i) {
        af0[i][0] = *(const bf16x8*)(As + i * 1024 + aro + k0off);
        af0[i][1] = *(const bf16x8*)(As + i * 1024 + aro + k1off);
    }
#pragma unroll
    for (int j = 0; j < 2; ++j) {
        bf0[j][0] = *(const bf16x8*)(Bs + j * 1024 + bro + k0off);
        bf0[j][1] = *(const bf16x8*)(Bs + j * 1024 + bro + k1off);
    }

    for (int u = 0; u < nt; ++u) {
        const ushort* Asl = As + (u & 1) * 16384;
        const ushort* Bsl = Bs + (u & 1) * 16384;
        const ushort* Asn = As + ((u & 1) ^ 1) * 16384;
        const ushort* Bsn = Bs + ((u & 1) ^ 1) * 16384;
        const bool st = (u + 2 < nt);
        const bool rd = (u + 1 < nt);

        // ---- P1: stage B-h0(u+2); read af1(u); MFMA(0,0) af0*bf0 ----
        if (st) { SB(u + 2, 0, 0); SB(u + 2, 0, 1); }
#pragma unroll
        for (int i = 0; i < 4; ++i) {
            af1[i][0] = *(const bf16x8*)(Asl + 8192 + i * 1024 + aro + k0off);
            af1[i][1] = *(const bf16x8*)(Asl + 8192 + i * 1024 + aro + k1off);
        }
        MFMA_Q(0, 0, af0, bf0);
        // no barrier: P2's stage WAR is covered by P4(u-1)'s lgkmcnt(0)+barrier

        // ---- P2: stage A-h0(u+2); read bf1(u); MFMA(1,0) af1*bf0 ----
        if (st) { SA(u + 2, 0, 0); SA(u + 2, 0, 1); }
#pragma unroll
        for (int j = 0; j < 2; ++j) {
            bf1[j][0] = *(const bf16x8*)(Bsl + 8192 + j * 1024 + bro + k0off);
            bf1[j][1] = *(const bf16x8*)(Bsl + 8192 + j * 1024 + bro + k1off);
        }
        MFMA_Q(1, 0, af1, bf0);
        if (st) asm volatile("s_waitcnt vmcnt(8)" ::: "memory");
        else    asm volatile("s_waitcnt vmcnt(0)" ::: "memory");
        __builtin_amdgcn_s_barrier();   // h0(u+1) landed for all waves

        // ---- P3: stage A-h1(u+2); read bf0(u+1) from next slot; MFMA(0,1) ----
        if (st) { SA(u + 2, 1, 0); SA(u + 2, 1, 1); }
        if (rd) {
#pragma unroll
            for (int j = 0; j < 2; ++j) {
                bf0[j][0] = *(const bf16x8*)(Bsn + j * 1024 + bro + k0off);
                bf0[j][1] = *(const bf16x8*)(Bsn + j * 1024 + bro + k1off);
            }
        }
        MFMA_Q(0, 1, af0, bf1);
        __builtin_amdgcn_s_barrier();   // bf1 reads drained (MFMA-gated) before P4's B-h1 stage

        // ---- P4: stage B-h1(u+2); read af0(u+1); MFMA(1,1) af1*bf1 ----
        if (st) { SB(u + 2, 1, 0); SB(u + 2, 1, 1); }
        if (rd) {
#pragma unroll
            for (int i = 0; i < 4; ++i) {
                af0[i][0] = *(const bf16x8*)(Asn + i * 1024 + aro + k0off);
                af0[i][1] = *(const bf16x8*)(Asn + i * 1024 + aro + k1off);
            }
        }
        MFMA_Q(1, 1, af1, bf1);
        asm volatile("s_waitcnt lgkmcnt(0)" ::: "memory");  // drain bf0/af0 refills (WAR guard)
        if (st) asm volatile("s_waitcnt vmcnt(8)" ::: "memory");
        else    asm volatile("s_waitcnt vmcnt(0)" ::: "memory");
        __builtin_amdgcn_s_barrier();   // tile u+1 fully landed; slot regions reusable
    }
#undef SA
#undef SB
#undef MFMA_Q

    // epilogue: C/D layout col=lane&15, row=quad*4+reg  [verified m89/m91]
    const int gm0 = bm * 256 + wm * 128;
    const int gn0 = bn * 256 + wn * 64;
    float bv[4];
#pragma unroll
    for (int j = 0; j < 4; ++j) bv[j] = bias[gn0 + j * 16 + l15];
#pragma unroll
    for (int i = 0; i < 8; ++i) {
#pragma unroll
        for (int j = 0; j < 4; ++j) {
            const int col = gn0 + j * 16 + l15;
#pragma unroll
            for (int r = 0; r < 4; ++r) {
                const int row = gm0 + i * 16 + quad * 4 + r;
                float v = acc[i][j][r] + bv[j];
                if (OUT_BF16)
                    ((ushort*)C)[(size_t)row * N + col] = f2b(v);
                else
                    ((float*)C)[(size_t)row * N + col] = v;
            }
        }
    }
}

// Pass A: per (b, chunk) compute affine (A_c scalar, B_c vector of D)
// 4-step batched loads so 4+ ushort4 loads are in flight per wave.
__global__ __launch_bounds__(256) void scan_partial(const ushort* __restrict__ upd,
                                                    const float* __restrict__ mask,
                                                    const float* __restrict__ dp,
                                                    float* __restrict__ Bc,
                                                    float* __restrict__ Ac,
                                                    int S, int D, int C) {
    const int c = blockIdx.x % C;
    const int b = blockIdx.x / C;
    const int L = S / C;
    const int d0 = threadIdx.x * 4;
    const float decay = 1.f / (1.f + expf(-dp[0]));
    const ushort* up = upd + ((size_t)b * S + (size_t)c * L) * D + d0;
    const float* mp = mask + (size_t)b * S + (size_t)c * L;
    float aA = 1.f;
    float b0 = 0.f, b1 = 0.f, b2 = 0.f, b3 = 0.f;
    for (int s0 = 0; s0 < L; s0 += 4) {
        float4 mv = *(const float4*)(mp + s0);
        ushort4 u0 = *(const ushort4*)(up + (size_t)(s0 + 0) * D);
        ushort4 u1 = *(const ushort4*)(up + (size_t)(s0 + 1) * D);
        ushort4 u2 = *(const ushort4*)(up + (size_t)(s0 + 2) * D);
        ushort4 u3 = *(const ushort4*)(up + (size_t)(s0 + 3) * D);
        float m, a;
        m = mv.x; a = m * decay + (1.f - m); aA *= a;
        b0 = a * b0 + m * b2f(u0.x); b1 = a * b1 + m * b2f(u0.y);
        b2 = a * b2 + m * b2f(u0.z); b3 = a * b3 + m * b2f(u0.w);
        m = mv.y; a = m * decay + (1.f - m); aA *= a;
        b0 = a * b0 + m * b2f(u1.x); b1 = a * b1 + m * b2f(u1.y);
        b2 = a * b2 + m * b2f(u1.z); b3 = a * b3 + m * b2f(u1.w);
        m = mv.z; a = m * decay + (1.f - m); aA *= a;
        b0 = a * b0 + m * b2f(u2.x); b1 = a * b1 + m * b2f(u2.y);
        b2 = a * b2 + m * b2f(u2.z); b3 = a * b3 + m * b2f(u2.w);
        m = mv.w; a = m * decay + (1.f - m); aA *= a;
        b0 = a * b0 + m * b2f(u3.x); b1 = a * b1 + m * b2f(u3.y);
        b2 = a * b2 + m * b2f(u3.z); b3 = a * b3 + m * b2f(u3.w);
    }
    *(float4*)(Bc + (size_t)blockIdx.x * D + d0) = make_float4(b0, b1, b2, b3);
    if (threadIdx.x == 0) Ac[blockIdx.x] = aA;
}

// Pass B: serial prefix over C chunks per (b,d) chain; writes incoming state per chunk.
// 128-thread blocks -> 64 blocks: spreads the latency chains over more CUs.
__global__ __launch_bounds__(128) void scan_prefix(const float* __restrict__ Ac,
                                                   const float* __restrict__ Bc,
                                                   float* __restrict__ Mn, int D, int C) {
    int gid = blockIdx.x * 128 + threadIdx.x;  // over B*D
    int b = gid / D;
    int d = gid - b * D;
    float mem = 0.f;
    for (int c = 0; c < C; c += 4) {
        float4 av = *(const float4*)(Ac + b * C + c);
        size_t i0 = ((size_t)(b * C + c)) * D + d;
        float q0 = Bc[i0];
        float q1 = Bc[i0 + D];
        float q2 = Bc[i0 + 2 * (size_t)D];
        float q3 = Bc[i0 + 3 * (size_t)D];
        Mn[i0] = mem;                    mem = av.x * mem + q0;
        Mn[i0 + D] = mem;                mem = av.y * mem + q1;
        Mn[i0 + 2 * (size_t)D] = mem;    mem = av.z * mem + q2;
        Mn[i0 + 3 * (size_t)D] = mem;    mem = av.w * mem + q3;
    }
}

// Pass C: replay each chunk from its incoming state, write mem_seq (bf16)
__global__ __launch_bounds__(256) void scan_final(const ushort* __restrict__ upd,
                                                  const float* __restrict__ mask,
                                                  const float* __restrict__ dp,
                                                  const float* __restrict__ Mn,
                                                  ushort* __restrict__ ms,
                                                  int S, int D, int C) {
    const int c = blockIdx.x % C;
    const int b = blockIdx.x / C;
    const int L = S / C;
    const int d0 = threadIdx.x * 4;
    const float decay = 1.f / (1.f + expf(-dp[0]));
    const ushort* up = upd + ((size_t)b * S + (size_t)c * L) * D + d0;
    ushort* op = ms + ((size_t)b * S + (size_t)c * L) * D + d0;
    const float* mp = mask + (size_t)b * S + (size_t)c * L;
    float4 m0 = *(const float4*)(Mn + (size_t)blockIdx.x * D + d0);
    float v0 = m0.x, v1 = m0.y, v2 = m0.z, v3 = m0.w;
    for (int s0 = 0; s0 < L; s0 += 4) {
        float4 mv = *(const float4*)(mp + s0);
        ushort4 u0 = *(const ushort4*)(up + (size_t)(s0 + 0) * D);
        ushort4 u1 = *(const ushort4*)(up + (size_t)(s0 + 1) * D);
        ushort4 u2 = *(const ushort4*)(up + (size_t)(s0 + 2) * D);
        ushort4 u3 = *(const ushort4*)(up + (size_t)(s0 + 3) * D);
        float m, a;
        ushort4 o;
        m = mv.x; a = m * decay + (1.f - m);
        v0 = a * v0 + m * b2f(u0.x); v1 = a * v1 + m * b2f(u0.y);
        v2 = a * v2 + m * b2f(u0.z); v3 = a * v3 + m * b2f(u0.w);
        o.x = f2b(v0); o.y = f2b(v1); o.z = f2b(v2); o.w = f2b(v3);
        *(ushort4*)(op + (size_t)(s0 + 0) * D) = o;
        m = mv.y; a = m * decay + (1.f - m);
        v0 = a * v0 + m * b2f(u1.x); v1 = a * v1 + m * b2f(u1.y);
        v2 = a * v2 + m * b2f(u1.z); v3 = a * v3 + m * b2f(u1.w);
        o.x = f2b(v0); o.y = f2b(v1); o.z = f2b(v2); o.w = f2b(v3);
        *(ushort4*)(op + (size_t)(s0 + 1) * D) = o;
        m = mv.z; a = m * decay + (1.f - m);
        v0 = a * v0 + m * b2f(u2.x); v1 = a * v1 + m * b2f(u2.y);
        v2 = a * v2 + m * b2f(u2.z); v3 = a * v3 + m * b2f(u2.w);
        o.x = f2b(v0); o.y = f2b(v1); o.z = f2b(v2); o.w = f2b(v3);
        *(ushort4*)(op + (size_t)(s0 + 2) * D) = o;
        m = mv.w; a = m * decay + (1.f - m);
        v0 = a * v0 + m * b2f(u3.x); v1 = a * v1 + m * b2f(u3.y);
        v2 = a * v2 + m * b2f(u3.z); v3 = a * v3 + m * b2f(u3.w);
        o.x = f2b(v0); o.y = f2b(v1); o.z = f2b(v2); o.w = f2b(v3);
        *(ushort4*)(op + (size_t)(s0 + 3) * D) = o;
    }
}

extern "C" void kernel_launch(void* const* d_in, const int* in_sizes, int n_in,
                              void* d_out, int out_size, void* d_ws, size_t ws_size,
                              hipStream_t stream) {
    const float* x    = (const float*)d_in[0];
    const float* mask = (const float*)d_in[1];
    const float* Wu   = (const float*)d_in[2];
    const float* bu   = (const float*)d_in[3];
    const float* Wf   = (const float*)d_in[4];
    const float* bfv  = (const float*)d_in[5];
    const float* dp   = (const float*)d_in[6];

    const int B = PB, S = PS, D = PD;
    const int M = B * S;          // 32768
    const int C = 128;            // scan chunks; L = 32

    // workspace layout (bytes): total ~204 MB
    char* ws = (char*)d_ws;
    ushort* xb   = (ushort*)(ws);                 // 64 MB  bf16 x
    ushort* updb = (ushort*)(ws + 67108864);      // 64 MB  bf16 upd
    ushort* memb = (ushort*)(ws + 134217728);     // 64 MB  bf16 mem_seq
    ushort* Wub  = (ushort*)(ws + 201326592);     // 2 MB
    ushort* Wfb  = (ushort*)(ws + 203423744);     // 2 MB
    float*  Bc   = (float*)(ws + 205520896);      // 4 MB   B*C*D
    float*  Mn   = (float*)(ws + 209715200);      // 4 MB   B*C*D
    float*  Ac   = (float*)(ws + 213909504);      // 4 KB   B*C

    const int nx = B * S * D;
    cvt_f32_bf16<<<nx / 1024, 256, 0, stream>>>(x, xb, nx);
    cvt_w2<<<(2 * D * D) / 1024, 256, 0, stream>>>(Wu, Wf, Wub, Wfb, D * D);

    dim3 g1((M / 256) * (D / 256));  // 512 blocks, %8 == 0 for XCD swizzle
    gemm_bt<true><<<g1, 512, 0, stream>>>(xb, Wub, bu, (void*)updb, M, D, D);

    scan_partial<<<B * C, 256, 0, stream>>>(updb, mask, dp, Bc, Ac, S, D, C);
    scan_prefix<<<(B * D) / 128, 128, 0, stream>>>(Ac, Bc, Mn, D, C);
    scan_final<<<B * C, 256, 0, stream>>>(updb, mask, dp, Mn, memb, S, D, C);

    gemm_bt<false><<<g1, 512, 0, stream>>>(memb, Wfb, bfv, d_out, M, D, D);
}